// Round 1
// baseline (1043.842 us; speedup 1.0000x reference)
//
#include <hip/hip_runtime.h>
#include <hip/hip_bf16.h>

#define NS 2          // samples per thread
#define THREADS 256

struct Params { const float* p[15]; };

// LDS packing: for each layer, W (row-major [IN][OUT]) immediately followed by b[OUT].
// d_in order: inputs, W_fm,b_fm, W1,b1, Wp1,bp1, W2,b2, Wp2,bp2, W3,b3, prototypes, Wh, bh
__constant__ constexpr int k_offs[15]  = {0,128,144,400,416,608,620,716,724,756,760,776,780,820,834};
__constant__ constexpr int k_sizes[15] = {128,16,256,16,192,12,96,8,32,4,16,4,40,14,1};
#define W_TOTAL 835

__device__ __forceinline__ float fast_tanh(float x) {
    // tanh(x) = 1 - 2/(exp(2x)+1); v_exp + v_rcp, saturates correctly at +/-inf
    float e = __expf(2.0f * x);
    return fmaf(-2.0f, __builtin_amdgcn_rcpf(e + 1.0f), 1.0f);
}

template<int IN, int OUT>
__device__ __forceinline__ void dense2(const float (&x)[NS][16], float (&y)[NS][16],
                                       const float* __restrict__ Wb) {
    float acc[NS][OUT];
#pragma unroll
    for (int j = 0; j < OUT; ++j) {
        float bj = Wb[IN * OUT + j];
#pragma unroll
        for (int s = 0; s < NS; ++s) acc[s][j] = bj;
    }
#pragma unroll
    for (int k = 0; k < IN; ++k) {
        float xs[NS];
#pragma unroll
        for (int s = 0; s < NS; ++s) xs[s] = x[s][k];
#pragma unroll
        for (int j = 0; j < OUT; ++j) {
            float wkj = Wb[k * OUT + j];
#pragma unroll
            for (int s = 0; s < NS; ++s) acc[s][j] = fmaf(xs[s], wkj, acc[s][j]);
        }
    }
#pragma unroll
    for (int j = 0; j < OUT; ++j)
#pragma unroll
        for (int s = 0; s < NS; ++s) y[s][j] = fast_tanh(acc[s][j]);
}

__global__ __launch_bounds__(THREADS) void qcnn_fused(const float* __restrict__ inputs,
                                                      Params ps,
                                                      float* __restrict__ out,
                                                      int B) {
    __shared__ float w[W_TOTAL];
    // cooperative stage of all weights into LDS
#pragma unroll
    for (int p = 0; p < 15; ++p) {
        const float* src = ps.p[p];
        for (int i = threadIdx.x; i < k_sizes[p]; i += THREADS)
            w[k_offs[p] + i] = src[i];
    }
    __syncthreads();

    const int tid = blockIdx.x * THREADS + threadIdx.x;
    const int T   = gridDim.x * THREADS;

    int  sidx[NS];
    bool valid[NS];
#pragma unroll
    for (int s = 0; s < NS; ++s) {
        sidx[s]  = tid + s * T;
        valid[s] = sidx[s] < B;
    }

    // load 8 input features per sample (two float4 each, coalesced per instruction)
    float a[NS][16], b2buf[NS][16];
#pragma unroll
    for (int s = 0; s < NS; ++s) {
        int si = valid[s] ? sidx[s] : 0;
        const float4* in4 = reinterpret_cast<const float4*>(inputs) + (size_t)si * 2;
        float4 v0 = in4[0], v1 = in4[1];
        a[s][0] = v0.x; a[s][1] = v0.y; a[s][2] = v0.z; a[s][3] = v0.w;
        a[s][4] = v1.x; a[s][5] = v1.y; a[s][6] = v1.z; a[s][7] = v1.w;
    }

    dense2<8, 16>(a, b2buf, &w[0]);     // feature_map
    dense2<16, 16>(b2buf, a, &w[144]);  // conv1
    dense2<16, 12>(a, b2buf, &w[416]);  // pool1
    dense2<12, 8>(b2buf, a, &w[620]);   // conv2
    dense2<8, 4>(a, b2buf, &w[724]);    // pool2
    dense2<4, 4>(b2buf, a, &w[760]);    // conv3 -> a[s][0..3]

#pragma unroll
    for (int s = 0; s < NS; ++s) {
        // RBF kernel features vs 10 prototypes (GAMMA = 1)
        float kf[10];
#pragma unroll
        for (int j = 0; j < 10; ++j) {
            float d2 = 0.0f;
#pragma unroll
            for (int k = 0; k < 4; ++k) {
                float d = a[s][k] - w[780 + j * 4 + k];
                d2 = fmaf(d, d, d2);
            }
            kf[j] = __expf(-d2);
        }
        // head: Linear(4+10, 1) + sigmoid
        float acc = w[834];
#pragma unroll
        for (int k = 0; k < 4; ++k)  acc = fmaf(a[s][k], w[820 + k], acc);
#pragma unroll
        for (int j = 0; j < 10; ++j) acc = fmaf(kf[j], w[824 + j], acc);
        float res = __builtin_amdgcn_rcpf(1.0f + __expf(-acc));
        if (valid[s]) out[sidx[s]] = res;
    }
}

extern "C" void kernel_launch(void* const* d_in, const int* in_sizes, int n_in,
                              void* d_out, int out_size, void* d_ws, size_t ws_size,
                              hipStream_t stream) {
    const float* inputs = (const float*)d_in[0];
    Params ps;
    for (int i = 0; i < 15; ++i) ps.p[i] = (const float*)d_in[i + 1];
    float* out = (float*)d_out;
    const int B = in_sizes[0] / 8;

    const int blocks = (B + THREADS * NS - 1) / (THREADS * NS);
    qcnn_fused<<<blocks, THREADS, 0, stream>>>(inputs, ps, out, B);
}

// Round 6
// 68.863 us; speedup vs baseline: 15.1582x; 15.1582x over previous
//
#include <hip/hip_runtime.h>

#define THREADS 256

__device__ __forceinline__ float fast_tanh(float x) {
    // tanh(x) = 1 - 2/(exp(2x)+1);  exp(2x) = exp2(x * 2*log2(e))
    float e = __builtin_amdgcn_exp2f(x * 2.885390081777927f);
    return fmaf(-2.0f, __builtin_amdgcn_rcpf(e + 1.0f), 1.0f);
}

// y[j] = tanh(b[j] + sum_k x[k]*W[k][j]); W row-major [IN][OUT], uniform -> s_load
template<int IN, int OUT>
__device__ __forceinline__ void dense(const float* x, float* y,
                                      const float* __restrict__ W,
                                      const float* __restrict__ b) {
#pragma unroll
    for (int j = 0; j < OUT; ++j) {
        float acc = b[j];
#pragma unroll
        for (int k = 0; k < IN; ++k)
            acc = fmaf(x[k], W[k * OUT + j], acc);
        y[j] = fast_tanh(acc);
    }
}

__global__ __launch_bounds__(THREADS) void qcnn_fused(
        const float* __restrict__ inputs,
        const float* __restrict__ W_fm, const float* __restrict__ b_fm,
        const float* __restrict__ W1,  const float* __restrict__ b1,
        const float* __restrict__ Wp1, const float* __restrict__ bp1,
        const float* __restrict__ W2,  const float* __restrict__ b2,
        const float* __restrict__ Wp2, const float* __restrict__ bp2,
        const float* __restrict__ W3,  const float* __restrict__ b3,
        const float* __restrict__ protos,
        const float* __restrict__ Wh,  const float* __restrict__ bh,
        float* __restrict__ out, int B) {
    const int tid = blockIdx.x * THREADS + threadIdx.x;
    if (tid >= B) return;

    float xa[16], xb[16];

    // 8 input features, two coalesced float4 loads
    const float4* in4 = reinterpret_cast<const float4*>(inputs) + (size_t)tid * 2;
    float4 v0 = in4[0], v1 = in4[1];
    xa[0] = v0.x; xa[1] = v0.y; xa[2] = v0.z; xa[3] = v0.w;
    xa[4] = v1.x; xa[5] = v1.y; xa[6] = v1.z; xa[7] = v1.w;

    dense<8, 16>(xa, xb, W_fm, b_fm);  // feature_map
    dense<16, 16>(xb, xa, W1, b1);     // conv1
    dense<16, 12>(xa, xb, Wp1, bp1);   // pool1
    dense<12, 8>(xb, xa, W2, b2);      // conv2
    dense<8, 4>(xa, xb, Wp2, bp2);     // pool2
    dense<4, 4>(xb, xa, W3, b3);       // conv3 -> xa[0..3]

    // RBF kernel features vs 10 prototypes (GAMMA = 1): exp(-||x-p||^2)
    float acc = bh[0];
#pragma unroll
    for (int k = 0; k < 4; ++k) acc = fmaf(xa[k], Wh[k], acc);
#pragma unroll
    for (int j = 0; j < 10; ++j) {
        float d2 = 0.0f;
#pragma unroll
        for (int k = 0; k < 4; ++k) {
            float d = xa[k] - protos[j * 4 + k];
            d2 = fmaf(d, d, d2);
        }
        float kf = __builtin_amdgcn_exp2f(d2 * -1.4426950408889634f); // exp(-d2)
        acc = fmaf(kf, Wh[4 + j], acc);
    }
    // sigmoid
    float e = __builtin_amdgcn_exp2f(acc * -1.4426950408889634f);
    out[tid] = __builtin_amdgcn_rcpf(1.0f + e);
}

extern "C" void kernel_launch(void* const* d_in, const int* in_sizes, int n_in,
                              void* d_out, int out_size, void* d_ws, size_t ws_size,
                              hipStream_t stream) {
    const float* inputs = (const float*)d_in[0];
    float* out = (float*)d_out;
    const int B = in_sizes[0] / 8;
    const int blocks = (B + THREADS - 1) / THREADS;
    qcnn_fused<<<blocks, THREADS, 0, stream>>>(
        inputs,
        (const float*)d_in[1],  (const float*)d_in[2],
        (const float*)d_in[3],  (const float*)d_in[4],
        (const float*)d_in[5],  (const float*)d_in[6],
        (const float*)d_in[7],  (const float*)d_in[8],
        (const float*)d_in[9],  (const float*)d_in[10],
        (const float*)d_in[11], (const float*)d_in[12],
        (const float*)d_in[13],
        (const float*)d_in[14], (const float*)d_in[15],
        out, B);
}

// Round 7
// 53.114 us; speedup vs baseline: 19.6528x; 1.2965x over previous
//
#include <hip/hip_runtime.h>

#define THREADS 256
typedef float v2f __attribute__((ext_vector_type(2)));

// packed tanh on a pair: 3 packed VALU + 4 TRANS (vs 6 VALU + 4 TRANS scalar)
__device__ __forceinline__ v2f tanh2(v2f x) {
    v2f xs = x * 2.885390081777927f;               // v_pk_mul_f32  (2*log2e)
    v2f e  = { __builtin_amdgcn_exp2f(xs.x),
               __builtin_amdgcn_exp2f(xs.y) };      // 2x v_exp_f32
    v2f ep = e + 1.0f;                              // v_pk_add_f32
    v2f r  = { __builtin_amdgcn_rcpf(ep.x),
               __builtin_amdgcn_rcpf(ep.y) };       // 2x v_rcp_f32
    return (v2f){-2.0f, -2.0f} * r + 1.0f;          // v_pk_fma_f32
}

// y[j] = tanh(b[j] + sum_k x[k]*W[k][j]); OUT even, pairs -> v_pk_fma_f32
template<int IN, int OUT>
__device__ __forceinline__ void dense(const float* x, float* y,
                                      const float* __restrict__ W,
                                      const float* __restrict__ b) {
#pragma unroll
    for (int j = 0; j < OUT; j += 2) {
        v2f acc = { b[j], b[j + 1] };
#pragma unroll
        for (int k = 0; k < IN; ++k) {
            v2f w = { W[k * OUT + j], W[k * OUT + j + 1] };
            acc += w * x[k];                        // v_pk_fma_f32 (x broadcast)
        }
        v2f t = tanh2(acc);
        y[j] = t.x; y[j + 1] = t.y;
    }
}

__global__ __launch_bounds__(THREADS) void qcnn_fused(
        const float* __restrict__ inputs,
        const float* __restrict__ W_fm, const float* __restrict__ b_fm,
        const float* __restrict__ W1,  const float* __restrict__ b1,
        const float* __restrict__ Wp1, const float* __restrict__ bp1,
        const float* __restrict__ W2,  const float* __restrict__ b2,
        const float* __restrict__ Wp2, const float* __restrict__ bp2,
        const float* __restrict__ W3,  const float* __restrict__ b3,
        const float* __restrict__ protos,
        const float* __restrict__ Wh,  const float* __restrict__ bh,
        float* __restrict__ out, int B) {
    const int tid = blockIdx.x * THREADS + threadIdx.x;
    if (tid >= B) return;

    float xa[16], xb[16];

    const float4* in4 = reinterpret_cast<const float4*>(inputs) + (size_t)tid * 2;
    float4 v0 = in4[0], v1 = in4[1];
    xa[0] = v0.x; xa[1] = v0.y; xa[2] = v0.z; xa[3] = v0.w;
    xa[4] = v1.x; xa[5] = v1.y; xa[6] = v1.z; xa[7] = v1.w;

    dense<8, 16>(xa, xb, W_fm, b_fm);  // feature_map
    dense<16, 16>(xb, xa, W1, b1);     // conv1
    dense<16, 12>(xa, xb, Wp1, bp1);   // pool1
    dense<12, 8>(xb, xa, W2, b2);      // conv2
    dense<8, 4>(xa, xb, Wp2, bp2);     // pool2
    dense<4, 4>(xb, xa, W3, b3);       // conv3 -> xa[0..3]

    // head contribution of x (pairs), then RBF features vs 10 prototypes
    v2f ha = { bh[0], 0.0f };
    ha += (v2f){ xa[0], xa[1] } * (v2f){ Wh[0], Wh[1] };
    ha += (v2f){ xa[2], xa[3] } * (v2f){ Wh[2], Wh[3] };
    float acc = ha.x + ha.y;

#pragma unroll
    for (int j = 0; j < 10; j += 2) {
        v2f d2 = { 0.0f, 0.0f };
#pragma unroll
        for (int k = 0; k < 4; ++k) {
            v2f p = { protos[j * 4 + k], protos[(j + 1) * 4 + k] };
            v2f d = (v2f){ xa[k], xa[k] } - p;      // v_pk_add_f32 (sub)
            d2 += d * d;                            // v_pk_fma_f32
        }
        v2f d2s = d2 * -1.4426950408889634f;        // v_pk_mul_f32 (-log2e)
        float kf0 = __builtin_amdgcn_exp2f(d2s.x);  // exp(-d2)
        float kf1 = __builtin_amdgcn_exp2f(d2s.y);
        acc = fmaf(kf0, Wh[4 + j], acc);
        acc = fmaf(kf1, Wh[5 + j], acc);
    }
    // sigmoid
    float e = __builtin_amdgcn_exp2f(acc * -1.4426950408889634f);
    out[tid] = __builtin_amdgcn_rcpf(1.0f + e);
}

extern "C" void kernel_launch(void* const* d_in, const int* in_sizes, int n_in,
                              void* d_out, int out_size, void* d_ws, size_t ws_size,
                              hipStream_t stream) {
    const float* inputs = (const float*)d_in[0];
    float* out = (float*)d_out;
    const int B = in_sizes[0] / 8;
    const int blocks = (B + THREADS - 1) / THREADS;
    qcnn_fused<<<blocks, THREADS, 0, stream>>>(
        inputs,
        (const float*)d_in[1],  (const float*)d_in[2],
        (const float*)d_in[3],  (const float*)d_in[4],
        (const float*)d_in[5],  (const float*)d_in[6],
        (const float*)d_in[7],  (const float*)d_in[8],
        (const float*)d_in[9],  (const float*)d_in[10],
        (const float*)d_in[11], (const float*)d_in[12],
        (const float*)d_in[13],
        (const float*)d_in[14], (const float*)d_in[15],
        out, B);
}